// Round 9
// baseline (614.382 us; speedup 1.0000x reference)
//
#include <hip/hip_runtime.h>
#include <math.h>

#define IN_F 1433
#define HID  16
#define OUTC 7
#define SCAN_T 1024

// K1 geometry (v5: lane=k, transposed W1 in LDS, halving reduce)
#define K1_THREADS 512        // 8 waves
#define K1_ROWS_W  4          // rows per wave
#define K1_ROWS_B  32         // rows per block
#define KA         768        // phase-A k count (12 chunks of 64)
#define KTP        769        // transposed LDS k-stride (odd -> conflict-free)
#define K1_LDS_FLOATS (HID * KTP)   // 12304 floats = 49216 B

__host__ __device__ __forceinline__ int imin(int a, int b) { return a < b ? a : b; }

// ---------------------------------------------------------------------------
// zero_i32: cheap in-graph zeroing (cnt only; ecv pads zeroed in csr_scan)
// ---------------------------------------------------------------------------
__global__ __launch_bounds__(256) void zero_i32(int4* __restrict__ p, int n4)
{
    int i = blockIdx.x * blockDim.x + threadIdx.x;
    if (i < n4) p[i] = make_int4(0, 0, 0, 0);
}

// ---------------------------------------------------------------------------
// K1 v5 body: XW = x @ W1.
// - x loads: lane owns k = base + c*64 + lane -> 256B wave-contiguous/instr.
// - W1 transposed in LDS: sWT[j*769 + k] -> 16 conflict-free ds_read_b32.
// - acc[4][16]/lane; 63-shuffle halving all-reduce; lane bitrev6 -> (r,j);
//   one coalesced 256B store per wave.
// NO wave-level early return (all threads stage LDS).
// ---------------------------------------------------------------------------
#define RED(i) acc[(i) >> 4][(i) & 15]

__device__ __forceinline__ void k1_body(
    const float* __restrict__ x, const float* __restrict__ W1,
    float* __restrict__ XW, int N, int vbid, float* sWT)
{
    const int wave = threadIdx.x >> 6;
    const int lane = threadIdx.x & 63;
    const int row0 = vbid * K1_ROWS_B + wave * K1_ROWS_W;

    size_t xoff[K1_ROWS_W];
#pragma unroll
    for (int r = 0; r < K1_ROWS_W; ++r) {
        int row = row0 + r;
        if (row > N - 1) row = N - 1;       // clamp; store masked later
        if (row < 0) row = 0;
        xoff[r] = (size_t)row * IN_F;
    }

    float acc[K1_ROWS_W][16];
#pragma unroll
    for (int r = 0; r < K1_ROWS_W; ++r)
#pragma unroll
        for (int j = 0; j < 16; ++j) acc[r][j] = 0.f;

    // ---------------- phase A: k in [0, KA) ----------------
    for (int f = threadIdx.x; f < KA * HID; f += K1_THREADS)
        sWT[(f & 15) * KTP + (f >> 4)] = W1[f];
    __syncthreads();

#pragma unroll 2
    for (int c = 0; c < KA / 64; ++c) {       // 12 chunks
        const int kloc = c * 64 + lane;
        float xv[K1_ROWS_W];
#pragma unroll
        for (int r = 0; r < K1_ROWS_W; ++r) xv[r] = x[xoff[r] + kloc];
        float w[16];
#pragma unroll
        for (int j = 0; j < 16; ++j) w[j] = sWT[j * KTP + kloc];
#pragma unroll
        for (int r = 0; r < K1_ROWS_W; ++r)
#pragma unroll
            for (int j = 0; j < 16; ++j)
                acc[r][j] += xv[r] * w[j];
    }
    __syncthreads();

    // ---------------- phase B: k in [KA, IN_F) ----------------
    for (int f = threadIdx.x; f < (IN_F - KA) * HID; f += K1_THREADS)
        sWT[(f & 15) * KTP + (f >> 4)] = W1[KA * HID + f];
    __syncthreads();

    const int NB_CHUNKS = (IN_F - KA + 63) / 64;   // 11, last partial
#pragma unroll 2
    for (int c = 0; c < NB_CHUNKS; ++c) {
        const int kloc = c * 64 + lane;            // < 704 < KTP (in-bounds)
        const int k = KA + kloc;
        const bool ok = (k < IN_F);
        float xv[K1_ROWS_W];
#pragma unroll
        for (int r = 0; r < K1_ROWS_W; ++r)
            xv[r] = ok ? x[xoff[r] + k] : 0.f;     // 0 * stale-w == 0
        float w[16];
#pragma unroll
        for (int j = 0; j < 16; ++j) w[j] = sWT[j * KTP + kloc];
#pragma unroll
        for (int r = 0; r < K1_ROWS_W; ++r)
#pragma unroll
            for (int j = 0; j < 16; ++j)
                acc[r][j] += xv[r] * w[j];
    }

    // halving all-reduce over 64 lanes: 63 shuffles total.
    // After step s (mask 2^s), active values halve; lane bit s picks upper.
#pragma unroll
    for (int step = 0; step < 6; ++step) {
        const int m = 1 << step;
        const bool up = (lane & m) != 0;
        const int half = 32 >> step;
#pragma unroll
        for (int j = 0; j < half; ++j) {
            float a = RED(j), b = RED(j + half);
            float keepv = up ? b : a;
            float sendv = up ? a : b;
            float recv  = __shfl_xor(sendv, m);
            RED(j) = keepv + recv;
        }
    }

    // lane owns global acc index g = bitrev6(lane): r = g>>4, j = g&15
    const int g = ((lane & 1) << 5) | ((lane & 2) << 3) | ((lane & 4) << 1) |
                  ((lane & 8) >> 1) | ((lane & 16) >> 3) | ((lane & 32) >> 5);
    const int r   = g >> 4;
    const int j   = g & 15;
    const int row = row0 + r;
    if (row >= 0 && row < N)
        XW[(size_t)row * HID + j] = RED(0);
}

// ---------------------------------------------------------------------------
// hist / scatter bodies (grid-strided over a virtual sub-grid)
// ---------------------------------------------------------------------------
__device__ __forceinline__ void hist_body(
    const int* __restrict__ arow, int* __restrict__ cnt, int E, int hb, int nhb)
{
    const int tid = hb * K1_THREADS + threadIdx.x;
    const int stride = nhb * K1_THREADS;
    const int E4 = E >> 2;
    const int4* a4 = (const int4*)arow;
    for (int v = tid; v < E4; v += stride) {
        int4 r = a4[v];
        atomicAdd(&cnt[r.x], 1);
        atomicAdd(&cnt[r.y], 1);
        atomicAdd(&cnt[r.z], 1);
        atomicAdd(&cnt[r.w], 1);
    }
    for (int v = E4 * 4 + tid; v < E; v += stride) atomicAdd(&cnt[arow[v]], 1);
}

__device__ __forceinline__ void scatter_body(
    const int* __restrict__ arow, const int* __restrict__ acol,
    const float* __restrict__ aval, int* __restrict__ cursor,
    int2* __restrict__ ecv, int E, int sb, int nsb)
{
    const int tid = sb * K1_THREADS + threadIdx.x;
    const int stride = nsb * K1_THREADS;
    const int E4 = E >> 2;
    const int4*   ar4 = (const int4*)arow;
    const int4*   ac4 = (const int4*)acol;
    const float4* av4 = (const float4*)aval;
    for (int v = tid; v < E4; v += stride) {
        int4 r = ar4[v];
        int4 c = ac4[v];
        float4 val = av4[v];
        int p0 = atomicAdd(&cursor[r.x], 1);
        int p1 = atomicAdd(&cursor[r.y], 1);
        int p2 = atomicAdd(&cursor[r.z], 1);
        int p3 = atomicAdd(&cursor[r.w], 1);
        ecv[p0] = make_int2(c.x, __float_as_int(val.x));
        ecv[p1] = make_int2(c.y, __float_as_int(val.y));
        ecv[p2] = make_int2(c.z, __float_as_int(val.z));
        ecv[p3] = make_int2(c.w, __float_as_int(val.w));
    }
    for (int v = E4 * 4 + tid; v < E; v += stride) {
        int pos = atomicAdd(&cursor[arow[v]], 1);
        ecv[pos] = make_int2(acol[v], __float_as_int(aval[v]));
    }
}

// ---------------------------------------------------------------------------
// Fat kernels: K1 halves overlapped with hist / scatter.
// Every 3rd block (bid%3==2, first `aux` of them) does the aux role.
// ---------------------------------------------------------------------------
__global__ __launch_bounds__(K1_THREADS) void k1_hist_fused(
    const float* __restrict__ x, const float* __restrict__ W1,
    float* __restrict__ XW, int N, int half1,
    const int* __restrict__ arow, int* __restrict__ cnt, int E, int histB)
{
    __shared__ float sWT[K1_LDS_FLOATS];
    const int bid = blockIdx.x;
    if ((bid % 3 == 2) && (bid / 3 < histB)) {
        hist_body(arow, cnt, E, bid / 3, histB);
        return;
    }
    const int k1_idx = bid - imin((bid + 1) / 3, histB);
    if (k1_idx >= half1) return;
    k1_body(x, W1, XW, N, k1_idx, sWT);
}

__global__ __launch_bounds__(K1_THREADS) void k1_scatter_fused(
    const float* __restrict__ x, const float* __restrict__ W1,
    float* __restrict__ XW, int N, int half1, int half2,
    const int* __restrict__ arow, const int* __restrict__ acol,
    const float* __restrict__ aval, int* __restrict__ cursor,
    int2* __restrict__ ecv, int E, int scb)
{
    __shared__ float sWT[K1_LDS_FLOATS];
    const int bid = blockIdx.x;
    if ((bid % 3 == 2) && (bid / 3 < scb)) {
        scatter_body(arow, acol, aval, cursor, ecv, E, bid / 3, scb);
        return;
    }
    const int k1_idx = bid - imin((bid + 1) / 3, scb) + half1;
    if (k1_idx >= half1 + half2) return;
    k1_body(x, W1, XW, N, k1_idx, sWT);
}

// plain K1 wrapper (fallback / degenerate paths)
__global__ __launch_bounds__(K1_THREADS) void gcn_k1_xw(
    const float* __restrict__ x, const float* __restrict__ W1,
    float* __restrict__ XW, int N)
{
    __shared__ float sWT[K1_LDS_FLOATS];
    k1_body(x, W1, XW, N, blockIdx.x, sWT);
}

// plain hist / scatter (degenerate tiny-N path)
__global__ __launch_bounds__(256) void csr_hist(
    const int* __restrict__ arow, int* __restrict__ cnt, int E)
{
    int e = blockIdx.x * blockDim.x + threadIdx.x;
    if (e < E) atomicAdd(&cnt[arow[e]], 1);
}

__global__ __launch_bounds__(256) void csr_scatter(
    const int* __restrict__ arow, const int* __restrict__ acol,
    const float* __restrict__ aval, int* __restrict__ cursor,
    int2* __restrict__ ecv, int E)
{
    int e = blockIdx.x * blockDim.x + threadIdx.x;
    if (e >= E) return;
    int pos = atomicAdd(&cursor[arow[e]], 1);
    ecv[pos] = make_int2(acol[e], __float_as_int(aval[e]));
}

// ---------------------------------------------------------------------------
// csr_scan: single-block scan. Row starts rounded UP TO EVEN so every row
// segment begins 16B-aligned in ecv (dwordx4 edge loads). Odd rows get one
// pad slot, zeroed HERE (so the bulk ecv zero is not needed).
// ---------------------------------------------------------------------------
__global__ __launch_bounds__(SCAN_T) void csr_scan(
    const int* __restrict__ cnt, int* __restrict__ rowptr,
    int* __restrict__ cursor, int2* __restrict__ ecv, int N)
{
    __shared__ int sums[SCAN_T];
    const int t = threadIdx.x;
    const int chunk = (((N + SCAN_T - 1) / SCAN_T) + 3) & ~3;  // 4-aligned
    const int lo = t * chunk;
    int s = 0;
    const bool full = (lo + chunk <= N);
    if (full) {
        const int4* c4 = (const int4*)(cnt + lo);
#pragma unroll 4
        for (int i = 0; i < chunk / 4; ++i) {
            int4 v = c4[i];
            s += ((v.x + 1) & ~1) + ((v.y + 1) & ~1)
               + ((v.z + 1) & ~1) + ((v.w + 1) & ~1);
        }
    } else {
        const int hi = (lo + chunk < N) ? lo + chunk : N;
        for (int i = lo; i < hi; ++i) s += (cnt[i] + 1) & ~1;
    }
    sums[t] = s;
    __syncthreads();
    for (int d = 1; d < SCAN_T; d <<= 1) {
        int a = sums[t];
        int b = (t >= d) ? sums[t - d] : 0;
        __syncthreads();
        sums[t] = a + b;
        __syncthreads();
    }
    int run = sums[t] - s;  // exclusive prefix (padded)
    const int2 zero2 = make_int2(0, 0);
    if (full) {
        const int4* c4 = (const int4*)(cnt + lo);
        int4* rp4 = (int4*)(rowptr + lo);
        int4* cu4 = (int4*)(cursor + lo);
        for (int i = 0; i < chunk / 4; ++i) {
            int4 v = c4[i];
            int4 o;
            o.x = run; if (v.x & 1) ecv[run + v.x] = zero2; run += (v.x + 1) & ~1;
            o.y = run; if (v.y & 1) ecv[run + v.y] = zero2; run += (v.y + 1) & ~1;
            o.z = run; if (v.z & 1) ecv[run + v.z] = zero2; run += (v.z + 1) & ~1;
            o.w = run; if (v.w & 1) ecv[run + v.w] = zero2; run += (v.w + 1) & ~1;
            rp4[i] = o;
            cu4[i] = o;
        }
    } else {
        const int hi = (lo + chunk < N) ? lo + chunk : N;
        for (int i = lo; i < hi; ++i) {
            rowptr[i] = run;
            cursor[i] = run;
            if (cnt[i] & 1) ecv[run + cnt[i]] = zero2;
            run += (cnt[i] + 1) & ~1;
        }
    }
    if (t == SCAN_T - 1) rowptr[N] = sums[SCAN_T - 1];
}

// ---------------------------------------------------------------------------
// SpMM(16) + relu(.+b1) @ W2 fused: one wave per row, 4 ways x 16 cols.
// Each way owns 4 CONTIGUOUS edges per iteration -> 2 aligned dwordx4 loads.
// ---------------------------------------------------------------------------
__global__ __launch_bounds__(256) void spmm16_h2(
    const int* __restrict__ rowptr, const int2* __restrict__ ecv,
    const float* __restrict__ XW, const float* __restrict__ b1,
    const float* __restrict__ W2, float* __restrict__ h2, int N)
{
    const int gw = (int)((blockIdx.x * (size_t)blockDim.x + threadIdx.x) >> 6);
    if (gw >= N) return;
    const int lane = threadIdx.x & 63;
    const int j = lane & 15;
    const int w = lane >> 4;
    const int s = rowptr[gw], e = rowptr[gw + 1];   // s,e even

    float acc = 0.f;
    int k = s + w * 4;
    while (k + 4 <= e) {
        const int4* q = (const int4*)(ecv + k);     // k even -> 16B aligned
        int4 A = q[0], B = q[1];
        float g0 = XW[(size_t)A.x * HID + j];
        float g1 = XW[(size_t)A.z * HID + j];
        float g2 = XW[(size_t)B.x * HID + j];
        float g3 = XW[(size_t)B.z * HID + j];
        acc += __int_as_float(A.y) * g0;
        acc += __int_as_float(A.w) * g1;
        acc += __int_as_float(B.y) * g2;
        acc += __int_as_float(B.w) * g3;
        k += 16;
    }
    for (; k < e; ++k) {                            // <=3 leftover this way
        int2 a = ecv[k];
        acc += __int_as_float(a.y) * XW[(size_t)a.x * HID + j];
    }
    // reduce the 4 edge-ways (lane bits 4,5)
    acc += __shfl_xor(acc, 16);
    acc += __shfl_xor(acc, 32);

    // fused layer-2 projection
    const float h = fmaxf(acc + b1[j], 0.f);
    float p[OUTC];
#pragma unroll
    for (int c = 0; c < OUTC; ++c) p[c] = h * W2[j * OUTC + c];
#pragma unroll
    for (int m = 1; m <= 8; m <<= 1)
#pragma unroll
        for (int c = 0; c < OUTC; ++c) p[c] += __shfl_xor(p[c], m);

    if (lane < 8) {
        float o = p[0];
        o = (lane == 1) ? p[1] : o;
        o = (lane == 2) ? p[2] : o;
        o = (lane == 3) ? p[3] : o;
        o = (lane == 4) ? p[4] : o;
        o = (lane == 5) ? p[5] : o;
        o = (lane == 6) ? p[6] : o;
        if (lane == 7) o = 0.f;           // pad col
        h2[(size_t)gw * 8 + lane] = o;
    }
}

// ---------------------------------------------------------------------------
// SpMM(7, stride-8 h2) + fused log_softmax: one wave per row, 8 ways x 8 cols.
// ---------------------------------------------------------------------------
__global__ __launch_bounds__(256) void spmm7_lsm(
    const int* __restrict__ rowptr, const int2* __restrict__ ecv,
    const float* __restrict__ h2, const float* __restrict__ b2,
    float* __restrict__ out, int N)
{
    const int gw = (int)((blockIdx.x * (size_t)blockDim.x + threadIdx.x) >> 6);
    if (gw >= N) return;
    const int lane = threadIdx.x & 63;
    const int j = lane & 7;
    const int w = lane >> 3;
    const int s = rowptr[gw], e = rowptr[gw + 1];

    float acc = 0.f;
    int k = s + w * 4;
    while (k + 4 <= e) {
        const int4* q = (const int4*)(ecv + k);
        int4 A = q[0], B = q[1];
        float g0 = h2[(size_t)A.x * 8 + j];
        float g1 = h2[(size_t)A.z * 8 + j];
        float g2 = h2[(size_t)B.x * 8 + j];
        float g3 = h2[(size_t)B.z * 8 + j];
        acc += __int_as_float(A.y) * g0;
        acc += __int_as_float(A.w) * g1;
        acc += __int_as_float(B.y) * g2;
        acc += __int_as_float(B.w) * g3;
        k += 32;
    }
    for (; k < e; ++k) {
        int2 a = ecv[k];
        acc += __int_as_float(a.y) * h2[(size_t)a.x * 8 + j];
    }
    // reduce the 8 edge-ways (lane bits 3,4,5)
    acc += __shfl_xor(acc, 8);
    acc += __shfl_xor(acc, 16);
    acc += __shfl_xor(acc, 32);

    const float bias = b2[(j < OUTC) ? j : 0];
    const float val  = acc + bias;
    float mx = (j < OUTC) ? val : -INFINITY;
    mx = fmaxf(mx, __shfl_xor(mx, 1));
    mx = fmaxf(mx, __shfl_xor(mx, 2));
    mx = fmaxf(mx, __shfl_xor(mx, 4));
    float ex = (j < OUTC) ? expf(val - mx) : 0.f;
    ex += __shfl_xor(ex, 1);
    ex += __shfl_xor(ex, 2);
    ex += __shfl_xor(ex, 4);
    if (lane < OUTC) out[(size_t)gw * OUTC + lane] = val - mx - logf(ex);
}

// ---------------------------------------------------------------------------
// Fallback path kernels (atomic-based, used only if ws too small)
// ---------------------------------------------------------------------------
__global__ __launch_bounds__(256) void gcn_k2_spmm16_atomic(
    const int* __restrict__ arow, const int* __restrict__ acol,
    const float* __restrict__ aval, const float* __restrict__ XW,
    float* __restrict__ H, int E)
{
    int e = blockIdx.x * blockDim.x + threadIdx.x;
    if (e >= E) return;
    const int r = arow[e], c = acol[e];
    const float v = aval[e];
    const float4* src = (const float4*)(XW + (size_t)c * HID);
    float4 a = src[0], b = src[1], cc = src[2], d = src[3];
    float* dst = H + (size_t)r * HID;
    atomicAdd(dst + 0,  v * a.x);  atomicAdd(dst + 1,  v * a.y);
    atomicAdd(dst + 2,  v * a.z);  atomicAdd(dst + 3,  v * a.w);
    atomicAdd(dst + 4,  v * b.x);  atomicAdd(dst + 5,  v * b.y);
    atomicAdd(dst + 6,  v * b.z);  atomicAdd(dst + 7,  v * b.w);
    atomicAdd(dst + 8,  v * cc.x); atomicAdd(dst + 9,  v * cc.y);
    atomicAdd(dst + 10, v * cc.z); atomicAdd(dst + 11, v * cc.w);
    atomicAdd(dst + 12, v * d.x);  atomicAdd(dst + 13, v * d.y);
    atomicAdd(dst + 14, v * d.z);  atomicAdd(dst + 15, v * d.w);
}

__global__ __launch_bounds__(256) void gcn_k3_h2(
    const float* __restrict__ H, const float* __restrict__ b1,
    const float* __restrict__ W2, float* __restrict__ h2, int N)
{
    __shared__ float sW2[HID * OUTC];
    __shared__ float sb1[HID];
    if (threadIdx.x < HID * OUTC) sW2[threadIdx.x] = W2[threadIdx.x];
    if (threadIdx.x < HID)        sb1[threadIdx.x] = b1[threadIdx.x];
    __syncthreads();

    int row = blockIdx.x * blockDim.x + threadIdx.x;
    if (row >= N) return;

    const float4* hp = (const float4*)(H + (size_t)row * HID);
    float4 h0 = hp[0], h1 = hp[1], h2v = hp[2], h3 = hp[3];
    float h[16] = {h0.x, h0.y, h0.z, h0.w, h1.x, h1.y, h1.z, h1.w,
                   h2v.x, h2v.y, h2v.z, h2v.w, h3.x, h3.y, h3.z, h3.w};
#pragma unroll
    for (int i = 0; i < HID; ++i) {
        h[i] += sb1[i];
        h[i] = h[i] > 0.f ? h[i] : 0.f;
    }
    float o[8];
#pragma unroll
    for (int jj = 0; jj < OUTC; ++jj) {
        float sum = 0.f;
#pragma unroll
        for (int i = 0; i < HID; ++i) sum += h[i] * sW2[i * OUTC + jj];
        o[jj] = sum;
    }
    o[7] = 0.f;
    float4* op = (float4*)(h2 + (size_t)row * 8);
    op[0] = make_float4(o[0], o[1], o[2], o[3]);
    op[1] = make_float4(o[4], o[5], o[6], o[7]);
}

__global__ __launch_bounds__(256) void gcn_k4_spmm7_atomic(
    const int* __restrict__ arow, const int* __restrict__ acol,
    const float* __restrict__ aval, const float* __restrict__ h2,
    float* __restrict__ out, int E)
{
    int e = blockIdx.x * blockDim.x + threadIdx.x;
    if (e >= E) return;
    const int r = arow[e], c = acol[e];
    const float v = aval[e];
    const float* src = h2 + (size_t)c * 8;
    float* dst = out + (size_t)r * OUTC;
#pragma unroll
    for (int jj = 0; jj < OUTC; ++jj) atomicAdd(dst + jj, v * src[jj]);
}

__global__ __launch_bounds__(256) void gcn_k5_lsm(
    float* __restrict__ out, const float* __restrict__ b2, int N)
{
    int row = blockIdx.x * blockDim.x + threadIdx.x;
    if (row >= N) return;
    float* p = out + (size_t)row * OUTC;
    float v[OUTC];
#pragma unroll
    for (int jj = 0; jj < OUTC; ++jj) v[jj] = p[jj] + b2[jj];
    float m = v[0];
#pragma unroll
    for (int jj = 1; jj < OUTC; ++jj) m = fmaxf(m, v[jj]);
    float s = 0.f;
#pragma unroll
    for (int jj = 0; jj < OUTC; ++jj) s += expf(v[jj] - m);
    const float ls = logf(s);
#pragma unroll
    for (int jj = 0; jj < OUTC; ++jj) p[jj] = v[jj] - m - ls;
}

// ---------------------------------------------------------------------------
extern "C" void kernel_launch(void* const* d_in, const int* in_sizes, int n_in,
                              void* d_out, int out_size, void* d_ws, size_t ws_size,
                              hipStream_t stream)
{
    const float* x    = (const float*)d_in[0];
    const int*   arow = (const int*)d_in[1];
    const int*   acol = (const int*)d_in[2];
    const float* aval = (const float*)d_in[3];
    const float* W1   = (const float*)d_in[4];
    const float* b1   = (const float*)d_in[5];
    const float* W2   = (const float*)d_in[6];
    const float* b2   = (const float*)d_in[7];
    float* out = (float*)d_out;

    const int N = in_sizes[0] / IN_F;
    const int E = in_sizes[1];

    // fast-path ws layout (16B-aligned chunks). ecv sized E+N (row padding).
    const int Np4  = (N + 3) & ~3;
    const int EPAD = E + N + 8;
    char* wsp = (char*)d_ws;
    int2*  ecv    = (int2*)wsp;   wsp += (size_t)EPAD * 8;
    int*   cnt    = (int*)wsp;    wsp += (size_t)Np4 * 4;
    int*   cursor = (int*)wsp;    wsp += (size_t)Np4 * 4;
    int*   rowptr = (int*)wsp;    wsp += (size_t)(Np4 + 4) * 4;
    float* XW     = (float*)wsp;  wsp += (size_t)N * HID * 4;
    float* h2     = (float*)wsp;  wsp += (size_t)N * 8 * 4;
    const size_t need = (size_t)(wsp - (char*)d_ws);

    const int eb  = (E + 255) / 256;
    const int nb  = (N + 255) / 256;
    const int k1b = (N + K1_ROWS_B - 1) / K1_ROWS_B;

    if (ws_size >= need) {
        // zero only cnt (ecv pad slots are zeroed inside csr_scan)
        const int n4z = Np4 / 4;
        zero_i32<<<(n4z + 255) / 256, 256, 0, stream>>>((int4*)cnt, n4z);

        const int half1 = (k1b + 1) / 2;
        const int half2 = k1b - half1;
        const int histB = imin(384, half1 / 2);
        const int scb   = imin(384, half2 / 2);

        if (histB >= 1 && scb >= 1) {
            // [K1 half1 || hist] -> scan -> [K1 half2 || scatter]
            k1_hist_fused<<<half1 + histB, K1_THREADS, 0, stream>>>(
                x, W1, XW, N, half1, arow, cnt, E, histB);
            csr_scan<<<1, SCAN_T, 0, stream>>>(cnt, rowptr, cursor, ecv, N);
            k1_scatter_fused<<<half2 + scb, K1_THREADS, 0, stream>>>(
                x, W1, XW, N, half1, half2, arow, acol, aval, cursor, ecv, E, scb);
        } else {
            // tiny N: plain sequential
            csr_hist<<<eb, 256, 0, stream>>>(arow, cnt, E);
            csr_scan<<<1, SCAN_T, 0, stream>>>(cnt, rowptr, cursor, ecv, N);
            csr_scatter<<<eb, 256, 0, stream>>>(arow, acol, aval, cursor, ecv, E);
            gcn_k1_xw<<<k1b, K1_THREADS, 0, stream>>>(x, W1, XW, N);
        }

        spmm16_h2<<<(N + 3) / 4, 256, 0, stream>>>(rowptr, ecv, XW, b1, W2, h2, N);
        spmm7_lsm<<<(N + 3) / 4, 256, 0, stream>>>(rowptr, ecv, h2, b2, out, N);
    } else {
        // ---- fallback: atomic path (needs only XW+H = 12.8 MB) ----
        float* XWf = (float*)d_ws;
        float* Hf  = XWf + (size_t)N * HID;
        float* h2f = XWf;   // XW dead after spmm16_atomic
        const int hz4 = (int)(((size_t)N * HID) / 4);
        zero_i32<<<(hz4 + 255) / 256, 256, 0, stream>>>((int4*)Hf, hz4);
        (void)hipMemsetAsync(out, 0, (size_t)N * OUTC * sizeof(float), stream);
        gcn_k1_xw<<<k1b, K1_THREADS, 0, stream>>>(x, W1, XWf, N);
        gcn_k2_spmm16_atomic<<<eb, 256, 0, stream>>>(arow, acol, aval, XWf, Hf, E);
        gcn_k3_h2<<<nb, 256, 0, stream>>>(Hf, b1, W2, h2f, N);
        gcn_k4_spmm7_atomic<<<eb, 256, 0, stream>>>(arow, acol, aval, h2f, out, E);
        gcn_k5_lsm<<<nb, 256, 0, stream>>>(out, b2, N);
    }
}